// Round 10
// baseline (499.020 us; speedup 1.0000x reference)
//
#include <hip/hip_runtime.h>
#include <math.h>

constexpr int B_ = 32;
constexpr int N_ = 1024;
constexpr int D_ = 64;
constexpr int BCH = 16;   // batch chunk; workspace ~211 MB (ws is ~268 MB)

typedef short short8 __attribute__((ext_vector_type(8)));   // 8 bf16 (4 VGPRs)
typedef float f32x4 __attribute__((ext_vector_type(4)));    // f32 MFMA accumulator
typedef int   int4_ __attribute__((ext_vector_type(4)));    // 16 i8 operand / i32x4 acc

__device__ __forceinline__ float sigf(float v) {
    return 1.0f / (1.0f + __expf(-v));
}
__device__ __forceinline__ unsigned short f2b(float f) {   // fp32 -> bf16 RNE
    unsigned u = __float_as_uint(f);
    unsigned r = u + 0x7fffu + ((u >> 16) & 1u);
    return (unsigned short)(r >> 16);
}
__device__ __forceinline__ float b2f(unsigned int h) {
    return __uint_as_float(h << 16);
}
__device__ __forceinline__ unsigned pack4(int a, int b, int c, int d) {
    return (unsigned)(a & 255) | ((unsigned)(b & 255) << 8) |
           ((unsigned)(c & 255) << 16) | ((unsigned)(d & 255) << 24);
}

#define GLD16(gp, lp)                                                        \
    __builtin_amdgcn_global_load_lds(                                        \
        (const __attribute__((address_space(1))) unsigned int*)(const void*)(gp), \
        (__attribute__((address_space(3))) unsigned int*)(void*)(lp), 16, 0, 0)

// ---------------------------------------------------------------- k_dots
__global__ void k_dots(const float* __restrict__ x,
                       const float* __restrict__ fw1, const float* __restrict__ fw2,
                       const float* __restrict__ gw1, const float* __restrict__ gw2,
                       const float* __restrict__ alpha,
                       float* __restrict__ e1f, float* __restrict__ e2f,
                       float* __restrict__ e1g, float* __restrict__ e2g,
                       float* __restrict__ sa)
{
    int t = blockIdx.x * blockDim.x + threadIdx.x;
    if (t < N_) sa[t] = sigf(alpha[t]);
    if (t >= B_ * N_) return;
    const float* xr = x + (size_t)t * D_;
    float s1 = 0.f, s2 = 0.f, s3 = 0.f, s4 = 0.f;
#pragma unroll 8
    for (int d = 0; d < D_; d++) {
        float v = xr[d];
        s1 += v * fw1[d];
        s2 += v * fw2[d];
        s3 += v * gw1[d];
        s4 += v * gw2[d];
    }
    e1f[t] = s1; e2f[t] = s2; e1g[t] = s3; e2g[t] = s4;
}

// ---------------------------------------------------------------- k_what2_split
__global__ void k_what2_split(const float* __restrict__ w, const float* __restrict__ dvec,
                              unsigned short* __restrict__ W2h, unsigned short* __restrict__ W2l)
{
    int t = blockIdx.x * blockDim.x + threadIdx.x;
    if (t >= D_ * D_) return;
    int i = t / D_, j = t % D_;
    float s = 0.f;
    for (int q = 0; q < D_; q++) {
        float dc = fminf(fmaxf(dvec[q], 0.0f), 1.0f);
        s += w[i * D_ + q] * dc * w[j * D_ + q];
    }
    if (i == j) s -= 2.0f;
    unsigned short h = f2b(s);
    W2h[t] = h;
    W2l[t] = f2b(s - b2f(h));
}

// ---------------------------------------------------------------- k_amix_split
__global__ void k_amix_split(const float* __restrict__ adj, const float* __restrict__ cw,
                             unsigned short* __restrict__ AmixH, unsigned short* __restrict__ AmixL)
{
    int t = blockIdx.x * blockDim.x + threadIdx.x;
    if (t >= N_ * N_) return;
    int i = t >> 10, j = t & (N_ - 1);
    float c0 = cw[0], c1 = cw[1];
    float v = c0 * adj[t] + c1 * adj[(size_t)N_ * N_ + t];
    if (i == j) v -= (c0 + c1);
    unsigned short h = f2b(v);
    AmixH[t] = h;
    AmixL[t] = f2b(v - b2f(h));
}

// ---------------------------------------------------------------- k_zinit / k_amax / k_aquant / k_zrs
__global__ void k_zinit(unsigned* __restrict__ amaxbits)
{
    if (threadIdx.x < 2) amaxbits[threadIdx.x] = 0;
}

__global__ void k_zrs(float* __restrict__ rsEF, float* __restrict__ rsEG)
{
    int t = blockIdx.x * blockDim.x + threadIdx.x;   // BCH*N threads
    rsEF[t] = 0.f;
    rsEG[t] = 0.f;
}

__global__ void k_amax(const float* __restrict__ fvs, const float* __restrict__ gvs,
                       unsigned* __restrict__ amaxbits)
{
    int fg = blockIdx.y;
    const float* src = fg ? gvs : fvs;
    int t = threadIdx.x;
    size_t base = ((size_t)blockIdx.x * 256 + t) * 16;
    float m = 0.f;
#pragma unroll
    for (int q = 0; q < 4; q++) {
        float4 v = *(const float4*)(src + base + q * 4);
        m = fmaxf(m, fmaxf(fmaxf(fabsf(v.x), fabsf(v.y)), fmaxf(fabsf(v.z), fabsf(v.w))));
    }
#pragma unroll
    for (int o = 32; o > 0; o >>= 1) m = fmaxf(m, __shfl_xor(m, o, 64));
    __shared__ float red[4];
    if ((t & 63) == 0) red[t >> 6] = m;
    __syncthreads();
    if (t == 0) {
        m = fmaxf(fmaxf(red[0], red[1]), fmaxf(red[2], red[3]));
        atomicMax(&amaxbits[fg], __float_as_uint(m));
    }
}

__launch_bounds__(256)
__global__ void k_aquant(const float* __restrict__ fvs, const float* __restrict__ gvs,
                         const float* __restrict__ amaxf,
                         signed char* __restrict__ AHf, signed char* __restrict__ ALf,
                         signed char* __restrict__ AHg, signed char* __restrict__ ALg,
                         float* __restrict__ rsumf, float* __restrict__ rsumg)
{
    int row = blockIdx.x;
    int fg  = blockIdx.y;
    const float* src = fg ? gvs : fvs;
    signed char* hp = fg ? AHg : AHf;
    signed char* lp = fg ? ALg : ALf;
    float* rs = fg ? rsumg : rsumf;
    float inv = 32512.f / amaxf[fg];
    int t = threadIdx.x;
    int j = t * 4;
    float4 v = *(const float4*)(src + (size_t)row * N_ + j);
    float a[4] = {v.x, v.y, v.z, v.w};
    int qh[4], ql[4], s = 0;
#pragma unroll
    for (int e = 0; e < 4; e++) {
        int q = __float2int_rn(a[e] * inv);
        q = min(max(q, -32512), 32512);
        int h = (q + 128) >> 8;
        qh[e] = h;
        ql[e] = q - (h << 8);
        s += q;
    }
    *(unsigned*)(hp + (size_t)row * N_ + j) = pack4(qh[0], qh[1], qh[2], qh[3]);
    *(unsigned*)(lp + (size_t)row * N_ + j) = pack4(ql[0], ql[1], ql[2], ql[3]);
#pragma unroll
    for (int o = 32; o > 0; o >>= 1) s += __shfl_xor(s, o, 64);
    __shared__ int red[4];
    if ((t & 63) == 0) red[t >> 6] = s;
    __syncthreads();
    if (t == 0) rs[row] = (float)(red[0] + red[1] + red[2] + red[3]);
}

// ---------------------------------------------------------------- k_xt_split
__launch_bounds__(256)
__global__ void k_xt_split(const float* __restrict__ xc,
                           unsigned short* __restrict__ XTh, unsigned short* __restrict__ XTl)
{
    int j0 = blockIdx.x * 64;
    int bc = blockIdx.y;
    int t  = threadIdx.x;
    __shared__ float S_l[64][65];
    {
        int j = t >> 2, dc = (t & 3) * 16;
        const float* src = xc + ((size_t)bc * N_ + j0 + j) * D_ + dc;
#pragma unroll
        for (int q = 0; q < 4; q++) {
            float4 v = *(const float4*)(src + q * 4);
            S_l[j][dc + q * 4 + 0] = v.x;
            S_l[j][dc + q * 4 + 1] = v.y;
            S_l[j][dc + q * 4 + 2] = v.z;
            S_l[j][dc + q * 4 + 3] = v.w;
        }
    }
    __syncthreads();
    {
        int d = t >> 2, jc = (t & 3) * 16;
        unsigned short hs[16], ls[16];
#pragma unroll
        for (int u = 0; u < 16; u++) {
            float v = S_l[jc + u][d];
            hs[u] = f2b(v);
            ls[u] = f2b(v - b2f(hs[u]));
        }
        uint4 hv0, hv1, lv0, lv1;
        hv0.x = hs[0] | (hs[1] << 16);  hv0.y = hs[2] | (hs[3] << 16);
        hv0.z = hs[4] | (hs[5] << 16);  hv0.w = hs[6] | (hs[7] << 16);
        hv1.x = hs[8] | (hs[9] << 16);  hv1.y = hs[10] | (hs[11] << 16);
        hv1.z = hs[12] | (hs[13] << 16); hv1.w = hs[14] | (hs[15] << 16);
        lv0.x = ls[0] | (ls[1] << 16);  lv0.y = ls[2] | (ls[3] << 16);
        lv0.z = ls[4] | (ls[5] << 16);  lv0.w = ls[6] | (ls[7] << 16);
        lv1.x = ls[8] | (ls[9] << 16);  lv1.y = ls[10] | (ls[11] << 16);
        lv1.z = ls[12] | (ls[13] << 16); lv1.w = ls[14] | (ls[15] << 16);
        size_t base = ((size_t)bc * D_ + d) * N_ + j0 + jc;
        *(uint4*)(XTh + base) = hv0;  *(uint4*)(XTh + base + 8) = hv1;
        *(uint4*)(XTl + base) = lv0;  *(uint4*)(XTl + base + 8) = lv1;
    }
}

// ---------------------------------------------------------------- k_sigsplit2
// grid (16 j-tiles, 16 k-tiles, 2 fg). One block stages the bs tile + all 16
// batches' e1/e2 strips once, then loops batches (bs read 1x instead of 16x).
__launch_bounds__(256)
__global__ void k_sigsplit2(const float* __restrict__ fbs, const float* __restrict__ gbs,
                            const float* __restrict__ e1f_, const float* __restrict__ e2f_,
                            const float* __restrict__ e1g_, const float* __restrict__ e2g_,
                            signed char* __restrict__ SHf, signed char* __restrict__ SLf,
                            signed char* __restrict__ SHg, signed char* __restrict__ SLg)
{
    int j0 = blockIdx.x * 64;
    int k0 = blockIdx.y * 64;
    int fg = blockIdx.z;
    const float* bs = fg ? gbs : fbs;
    const float* e1 = fg ? e1g_ : e1f_;
    const float* e2 = fg ? e2g_ : e2f_;
    signed char* SH = fg ? SHg : SHf;
    signed char* SL = fg ? SLg : SLf;
    int t  = threadIdx.x;

    __shared__ float bs_l[64][65];
    __shared__ float e1_l[BCH][64];
    __shared__ float e2_l[BCH][64];

    {
        int j = t >> 2, kc = (t & 3) * 16;
#pragma unroll
        for (int q = 0; q < 4; q++) {
            float4 v = *(const float4*)(bs + (size_t)(j0 + j) * N_ + k0 + kc + q * 4);
            bs_l[j][kc + q * 4 + 0] = v.x;
            bs_l[j][kc + q * 4 + 1] = v.y;
            bs_l[j][kc + q * 4 + 2] = v.z;
            bs_l[j][kc + q * 4 + 3] = v.w;
        }
#pragma unroll
        for (int i = 0; i < 4; i++) {
            int idx = t + i * 256;
            int b = idx >> 6, jj = idx & 63;
            e1_l[b][jj] = e1[(size_t)b * N_ + j0 + jj];
            e2_l[b][jj] = e2[(size_t)b * N_ + k0 + jj];
        }
    }
    __syncthreads();

    int k  = t >> 2;
    int jc = (t & 3) * 16;
    for (int b = 0; b < BCH; b++) {
        float e2k = e2_l[b][k];
        int hh[16], ll[16];
#pragma unroll
        for (int u = 0; u < 16; u++) {
            float v = sigf(fmaf(e1_l[b][jc + u], e2k, bs_l[jc + u][k]));
            int q = __float2int_rn(v * 65024.f) - 32512;
            q = min(max(q, -32512), 32512);
            int h = (q + 128) >> 8;
            hh[u] = h;
            ll[u] = q - (h << 8);
        }
        uint4 H, L;
        H.x = pack4(hh[0], hh[1], hh[2], hh[3]);   H.y = pack4(hh[4], hh[5], hh[6], hh[7]);
        H.z = pack4(hh[8], hh[9], hh[10], hh[11]); H.w = pack4(hh[12], hh[13], hh[14], hh[15]);
        L.x = pack4(ll[0], ll[1], ll[2], ll[3]);   L.y = pack4(ll[4], ll[5], ll[6], ll[7]);
        L.z = pack4(ll[8], ll[9], ll[10], ll[11]); L.w = pack4(ll[12], ll[13], ll[14], ll[15]);
        size_t base = (size_t)(b * N_ + k0 + k) * N_ + j0 + jc;
        *(uint4*)(SH + base) = H;
        *(uint4*)(SL + base) = L;
    }
}

// ---------------------------------------------------------------- k_gemm2i
// logit (fp32) = sA/65024 * (65536*M + 256*C + 32512*rsumA[i]).
// Epilogue also accumulates per-row sum(exp(logit)) into rsE via atomics.
__launch_bounds__(256, 2)
__global__ void k_gemm2i(const signed char* __restrict__ AHf, const signed char* __restrict__ ALf,
                         const signed char* __restrict__ AHg, const signed char* __restrict__ ALg,
                         const signed char* __restrict__ SHf, const signed char* __restrict__ SLf,
                         const signed char* __restrict__ SHg, const signed char* __restrict__ SLg,
                         const float* __restrict__ rsumf, const float* __restrict__ rsumg,
                         const float* __restrict__ amaxf,
                         float* __restrict__ LF, float* __restrict__ LG,
                         float* __restrict__ rsEF, float* __restrict__ rsEG)
{
    const int fg = blockIdx.z;
    const signed char* AH = fg ? AHg : AHf;
    const signed char* AL = fg ? ALg : ALf;
    const signed char* SH = fg ? SHg : SHf;
    const signed char* SL = fg ? SLg : SLf;
    const float* rsum = fg ? rsumg : rsumf;
    float* Lo  = fg ? LG : LF;
    float* rsE = fg ? rsEG : rsEF;
    const float scale = amaxf[fg] * (1.0f / (32512.f * 65024.f));

    const int b  = blockIdx.y;
    const int i0 = (blockIdx.x >> 3) * 128;
    const int k0 = (blockIdx.x & 7) * 128;
    const int t    = threadIdx.x;
    const int lane = t & 63;
    const int wave = t >> 6;
    const int wr   = wave >> 1;
    const int wc   = wave & 1;
    const int quad = lane >> 4;
    const int m16  = lane & 15;

    __shared__ __align__(16) signed char lds[32768];
    signed char* AHl = lds;
    signed char* ALl = lds + 8192;
    signed char* BHl = lds + 16384;
    signed char* BLl = lds + 24576;

    const signed char* gsrc;
    signed char* ldst;
    int rowbase;
    if (wave == 0)      { gsrc = AH; ldst = AHl; rowbase = i0; }
    else if (wave == 1) { gsrc = AL; ldst = ALl; rowbase = i0; }
    else if (wave == 2) { gsrc = SH; ldst = BHl; rowbase = b * N_ + k0; }
    else                { gsrc = SL; ldst = BLl; rowbase = b * N_ + k0; }

    int4_ accm[4][4], accc[4][4];
#pragma unroll
    for (int mi = 0; mi < 4; mi++)
#pragma unroll
        for (int ni = 0; ni < 4; ni++) {
            accm[mi][ni] = (int4_){0, 0, 0, 0};
            accc[mi][ni] = (int4_){0, 0, 0, 0};
        }

    const int rr = lane >> 2;
    const int cc = lane & 3;
    const int gcq = cc ^ ((rr >> 1) & 3);
    const int rpos = (quad ^ ((m16 >> 1) & 3)) * 16;

    for (int step = 0; step < 16; step++) {
        const int jb = step * 64;
        __syncthreads();
#pragma unroll
        for (int it = 0; it < 8; it++) {
            int r = it * 16 + rr;
            const signed char* gp = gsrc + (size_t)(rowbase + r) * N_ + jb + gcq * 16;
            GLD16(gp, ldst + it * 1024);
        }
        __syncthreads();

        int4_ ah[4], al[4];
#pragma unroll
        for (int mi = 0; mi < 4; mi++) {
            int row = wr * 64 + mi * 16 + m16;
            ah[mi] = *(const int4_*)(AHl + row * 64 + rpos);
            al[mi] = *(const int4_*)(ALl + row * 64 + rpos);
        }
#pragma unroll
        for (int ni = 0; ni < 4; ni++) {
            int row = wc * 64 + ni * 16 + m16;
            int4_ bh = *(const int4_*)(BHl + row * 64 + rpos);
            int4_ bl = *(const int4_*)(BLl + row * 64 + rpos);
#pragma unroll
            for (int mi = 0; mi < 4; mi++) {
                accm[mi][ni] = __builtin_amdgcn_mfma_i32_16x16x64_i8(
                    ah[mi], bh, accm[mi][ni], 0, 0, 0);
                accc[mi][ni] = __builtin_amdgcn_mfma_i32_16x16x64_i8(
                    ah[mi], bl, accc[mi][ni], 0, 0, 0);
                accc[mi][ni] = __builtin_amdgcn_mfma_i32_16x16x64_i8(
                    al[mi], bh, accc[mi][ni], 0, 0, 0);
            }
        }
    }

    float psum[4][4];
#pragma unroll
    for (int mi = 0; mi < 4; mi++)
#pragma unroll
        for (int r = 0; r < 4; r++) psum[mi][r] = 0.f;

#pragma unroll
    for (int mi = 0; mi < 4; mi++)
#pragma unroll
        for (int ni = 0; ni < 4; ni++) {
            int row = i0 + wr * 64 + mi * 16 + quad * 4;
            int col = k0 + wc * 64 + ni * 16 + m16;
            size_t base = ((size_t)b * N_ + row) * N_ + col;
#pragma unroll
            for (int r = 0; r < 4; r++) {
                float v = (65536.f * (float)accm[mi][ni][r] +
                           256.f * (float)accc[mi][ni][r] +
                           32512.f * rsum[row + r]) * scale;
                Lo[base + (size_t)r * N_] = v;
                psum[mi][r] += __expf(v);
            }
        }
    // reduce exp-partials across the 16 lanes sharing each row (same quad)
#pragma unroll
    for (int off = 1; off <= 8; off <<= 1)
#pragma unroll
        for (int mi = 0; mi < 4; mi++)
#pragma unroll
            for (int r = 0; r < 4; r++)
                psum[mi][r] += __shfl_xor(psum[mi][r], off, 16);
    if (m16 == 0) {
#pragma unroll
        for (int mi = 0; mi < 4; mi++)
#pragma unroll
            for (int r = 0; r < 4; r++) {
                int rowI = i0 + wr * 64 + mi * 16 + quad * 4 + r;
                atomicAdd(&rsE[(size_t)b * N_ + rowI], psum[mi][r]);
            }
    }
}

// ---------------------------------------------------------------- k_fused
// Per block: 32-row strip, both outputs. Row sums of exp come from k_gemm2i
// epilogue atomics (rsEF/rsEG) — no pre-pass over the logits.
__launch_bounds__(256, 2)
__global__ void k_fused(const float* __restrict__ LF, const float* __restrict__ LG,
                        const float* __restrict__ rsEF, const float* __restrict__ rsEG,
                        const unsigned short* __restrict__ AmixH, const unsigned short* __restrict__ AmixL,
                        const unsigned short* __restrict__ XTh, const unsigned short* __restrict__ XTl,
                        const unsigned short* __restrict__ W2h, const unsigned short* __restrict__ W2l,
                        const float* __restrict__ xc, const float* __restrict__ x0c,
                        const float* __restrict__ sa, const float* __restrict__ cb,
                        float* __restrict__ outf, float* __restrict__ outg)
{
    const int i0 = blockIdx.x * 32;
    const int bc = blockIdx.y;
    const int t    = threadIdx.x;
    const int lane = t & 63;
    const int wave = t >> 6;
    const int quad = lane >> 4;
    const int m16  = lane & 15;
    const int l7   = lane & 7;
    const int r_sub = lane >> 3;
    const int gc    = l7 ^ r_sub;

    __shared__ __align__(16) unsigned short lds[18432];   // 36 KB
    unsigned short* E_l  = lds;            // 32x64
    unsigned short* Nh_l = lds + 2048;
    unsigned short* Nl_l = lds + 4096;
    unsigned short* Xh_l = lds + 6144;     // 64x64
    unsigned short* Xl_l = lds + 10240;
    unsigned short* Ah_l = lds + 14336;    // 32x64
    unsigned short* Al_l = lds + 16384;
    __shared__ float invf_l[32], invg_l[32];

    if (t < 32)       invf_l[t]      = 1.0f / rsEF[(size_t)bc * N_ + i0 + t];
    else if (t < 64)  invg_l[t - 32] = 1.0f / rsEG[(size_t)bc * N_ + i0 + (t - 32)];

    f32x4 accf[2], accg[2];
#pragma unroll
    for (int u = 0; u < 2; u++) {
        accf[u] = (f32x4){0.f, 0.f, 0.f, 0.f};
        accg[u] = (f32x4){0.f, 0.f, 0.f, 0.f};
    }
    const int rowA = (wave & 1) * 16 + m16;   // 0..31
    const int cg0  = (wave >> 1) * 2;         // 0 or 2

    for (int step = 0; step < 16; step++) {
        const int jb = step * 64;
        __syncthreads();
        // GLD16: XTh(8) XTl(8) AmH(4) AmL(4) = 24 issues, 6 per wave
        for (int i = 0; i < 6; i++) {
            int gi = wave * 6 + i;
            const unsigned short* gp;
            unsigned short* lp;
            if (gi < 8) {
                gp = XTh + ((size_t)bc * D_ + gi * 8 + r_sub) * N_ + jb + gc * 8;
                lp = Xh_l + gi * 512;
            } else if (gi < 16) {
                int g2 = gi - 8;
                gp = XTl + ((size_t)bc * D_ + g2 * 8 + r_sub) * N_ + jb + gc * 8;
                lp = Xl_l + g2 * 512;
            } else if (gi < 20) {
                int g2 = gi - 16;
                gp = AmixH + (size_t)(i0 + g2 * 8 + r_sub) * N_ + jb + gc * 8;
                lp = Ah_l + g2 * 512;
            } else {
                int g2 = gi - 20;
                gp = AmixL + (size_t)(i0 + g2 * 8 + r_sub) * N_ + jb + gc * 8;
                lp = Al_l + g2 * 512;
            }
            GLD16(gp, lp);
        }
        // VALU staging: E / Nhat tiles
        {
            int r  = t >> 3;
            int jc = (t & 7) * 8;
            const float* lf = LF + ((size_t)bc * N_ + i0 + r) * N_ + jb + jc;
            const float* lg = LG + ((size_t)bc * N_ + i0 + r) * N_ + jb + jc;
            float4 f0 = *(const float4*)lf;
            float4 f1 = *(const float4*)(lf + 4);
            float4 g0 = *(const float4*)lg;
            float4 g1 = *(const float4*)(lg + 4);
            float fa[8] = {f0.x, f0.y, f0.z, f0.w, f1.x, f1.y, f1.z, f1.w};
            float ga[8] = {g0.x, g0.y, g0.z, g0.w, g1.x, g1.y, g1.z, g1.w};
            float fi = invf_l[r], gi2 = invg_l[r];
            short8 ev, nhv, nlv;
#pragma unroll
            for (int e = 0; e < 8; e++) {
                float E = __expf(fa[e]) * fi;
                float nh = __expf(ga[e]) * gi2 / (E + 1e-5f);
                ev[e] = (short)f2b(E);
                unsigned short h = f2b(nh);
                nhv[e] = (short)h;
                nlv[e] = (short)f2b(nh - b2f(h));
            }
            int pos = (((jc >> 3) ^ (r & 7))) * 8;
            *(short8*)(E_l  + r * 64 + pos) = ev;
            *(short8*)(Nh_l + r * 64 + pos) = nhv;
            *(short8*)(Nl_l + r * 64 + pos) = nlv;
        }
        __syncthreads();
#pragma unroll
        for (int kc = 0; kc < 2; kc++) {
            const int ch = ((kc * 4 + quad) ^ l7) * 8;
            short8 e  = *(const short8*)(E_l  + rowA * 64 + ch);
            short8 ah = *(const short8*)(Ah_l + rowA * 64 + ch);
            short8 al = *(const short8*)(Al_l + rowA * 64 + ch);
            short8 nh = *(const short8*)(Nh_l + rowA * 64 + ch);
            short8 nl = *(const short8*)(Nl_l + rowA * 64 + ch);
#pragma unroll
            for (int u = 0; u < 2; u++) {
                int rowB = (cg0 + u) * 16 + m16;
                short8 bh = *(const short8*)(Xh_l + rowB * 64 + ch);
                short8 bl = *(const short8*)(Xl_l + rowB * 64 + ch);
                accf[u] = __builtin_amdgcn_mfma_f32_16x16x32_bf16(e,  bh, accf[u], 0, 0, 0);
                accf[u] = __builtin_amdgcn_mfma_f32_16x16x32_bf16(e,  bl, accf[u], 0, 0, 0);
                accf[u] = __builtin_amdgcn_mfma_f32_16x16x32_bf16(ah, bh, accf[u], 0, 0, 0);
                accf[u] = __builtin_amdgcn_mfma_f32_16x16x32_bf16(ah, bl, accf[u], 0, 0, 0);
                accf[u] = __builtin_amdgcn_mfma_f32_16x16x32_bf16(al, bh, accf[u], 0, 0, 0);
                accg[u] = __builtin_amdgcn_mfma_f32_16x16x32_bf16(nh, bh, accg[u], 0, 0, 0);
                accg[u] = __builtin_amdgcn_mfma_f32_16x16x32_bf16(nh, bl, accg[u], 0, 0, 0);
                accg[u] = __builtin_amdgcn_mfma_f32_16x16x32_bf16(nl, bh, accg[u], 0, 0, 0);
            }
        }
    }

    // ---- phase B: f += x_rows @ What2 (one K=64 step; What2 symmetric) ----
    __syncthreads();
    {
        for (int i = 0; i < 4; i++) {
            int gi = wave * 4 + i;
            const unsigned short* gsrc2 = (gi < 8) ? W2h : W2l;
            int g2 = gi & 7;
            unsigned short* lp = ((gi < 8) ? Xh_l : Xl_l) + g2 * 512;
            GLD16(gsrc2 + (size_t)(g2 * 8 + r_sub) * 64 + gc * 8, lp);
        }
        int r  = t >> 3;
        int dc = (t & 7) * 8;
        const float* xrow = xc + ((size_t)bc * N_ + i0 + r) * D_ + dc;
        float4 v0 = *(const float4*)xrow;
        float4 v1 = *(const float4*)(xrow + 4);
        float vv[8] = {v0.x, v0.y, v0.z, v0.w, v1.x, v1.y, v1.z, v1.w};
        short8 hh, ll;
#pragma unroll
        for (int e = 0; e < 8; e++) {
            unsigned short h = f2b(vv[e]);
            hh[e] = (short)h;
            ll[e] = (short)f2b(vv[e] - b2f(h));
        }
        int pos = (((dc >> 3) ^ (r & 7))) * 8;
        *(short8*)(E_l  + r * 64 + pos) = hh;
        *(short8*)(Nh_l + r * 64 + pos) = ll;
    }
    __syncthreads();
#pragma unroll
    for (int kc = 0; kc < 2; kc++) {
        const int ch = ((kc * 4 + quad) ^ l7) * 8;
        short8 xh = *(const short8*)(E_l  + rowA * 64 + ch);
        short8 xl = *(const short8*)(Nh_l + rowA * 64 + ch);
#pragma unroll
        for (int u = 0; u < 2; u++) {
            int rowB = (cg0 + u) * 16 + m16;
            short8 bh = *(const short8*)(Xh_l + rowB * 64 + ch);
            short8 bl = *(const short8*)(Xl_l + rowB * 64 + ch);
            accf[u] = __builtin_amdgcn_mfma_f32_16x16x32_bf16(xh, bh, accf[u], 0, 0, 0);
            accf[u] = __builtin_amdgcn_mfma_f32_16x16x32_bf16(xh, bl, accf[u], 0, 0, 0);
            accf[u] = __builtin_amdgcn_mfma_f32_16x16x32_bf16(xl, bh, accf[u], 0, 0, 0);
        }
    }

    float cbv = cb[0];
#pragma unroll
    for (int u = 0; u < 2; u++) {
#pragma unroll
        for (int r = 0; r < 4; r++) {
            int row = i0 + (wave & 1) * 16 + quad * 4 + r;
            int col = (cg0 + u) * 16 + m16;
            size_t o = ((size_t)bc * N_ + row) * D_ + col;
            outf[o] = tanhf(accf[u][r] + x0c[o] * sa[row] + cbv);
            outg[o] = tanhf(accg[u][r]);
        }
    }
}

// ---------------------------------------------------------------- host
extern "C" void kernel_launch(void* const* d_in, const int* in_sizes, int n_in,
                              void* d_out, int out_size, void* d_ws, size_t ws_size,
                              hipStream_t stream)
{
    const float* x     = (const float*)d_in[0];
    const float* x0    = (const float*)d_in[1];
    const float* w     = (const float*)d_in[2];
    const float* dvec  = (const float*)d_in[3];
    const float* alpha = (const float*)d_in[4];
    const float* fw1   = (const float*)d_in[5];
    const float* fw2   = (const float*)d_in[6];
    const float* fvs   = (const float*)d_in[7];
    const float* fbs   = (const float*)d_in[8];
    const float* gw1   = (const float*)d_in[9];
    const float* gw2   = (const float*)d_in[10];
    const float* gvs   = (const float*)d_in[11];
    const float* gbs   = (const float*)d_in[12];
    const float* cw    = (const float*)d_in[13];
    const float* cb    = (const float*)d_in[14];
    const float* adj   = (const float*)d_in[15];

    float* outf = (float*)d_out;
    float* outg = outf + (size_t)B_ * N_ * D_;

    char* p = (char*)d_ws;
    auto alloc = [&](size_t bytes) { void* r = p; p += (bytes + 255) & ~(size_t)255; return r; };

    float* e1f = (float*)alloc(B_ * N_ * 4);
    float* e2f = (float*)alloc(B_ * N_ * 4);
    float* e1g = (float*)alloc(B_ * N_ * 4);
    float* e2g = (float*)alloc(B_ * N_ * 4);
    float* sa  = (float*)alloc(N_ * 4);
    unsigned short* W2h = (unsigned short*)alloc(D_ * D_ * 2);
    unsigned short* W2l = (unsigned short*)alloc(D_ * D_ * 2);
    float* amaxf = (float*)alloc(2 * 4);
    float* rsumf = (float*)alloc(N_ * 4);
    float* rsumg = (float*)alloc(N_ * 4);
    float* rsEF  = (float*)alloc((size_t)BCH * N_ * 4);
    float* rsEG  = (float*)alloc((size_t)BCH * N_ * 4);
    unsigned short* AmixH = (unsigned short*)alloc((size_t)N_ * N_ * 2);
    unsigned short* AmixL = (unsigned short*)alloc((size_t)N_ * N_ * 2);
    signed char* AHf = (signed char*)alloc((size_t)N_ * N_);
    signed char* ALf = (signed char*)alloc((size_t)N_ * N_);
    signed char* AHg = (signed char*)alloc((size_t)N_ * N_);
    signed char* ALg = (signed char*)alloc((size_t)N_ * N_);
    unsigned short* XTh = (unsigned short*)alloc((size_t)BCH * D_ * N_ * 2);
    unsigned short* XTl = (unsigned short*)alloc((size_t)BCH * D_ * N_ * 2);
    signed char* SHf = (signed char*)alloc((size_t)BCH * N_ * N_);
    signed char* SLf = (signed char*)alloc((size_t)BCH * N_ * N_);
    signed char* SHg = (signed char*)alloc((size_t)BCH * N_ * N_);
    signed char* SLg = (signed char*)alloc((size_t)BCH * N_ * N_);
    float* LF = (float*)alloc((size_t)BCH * N_ * N_ * 4);
    float* LG = (float*)alloc((size_t)BCH * N_ * N_ * 4);
    (void)ws_size; (void)in_sizes; (void)n_in; (void)out_size;

    k_zinit<<<dim3(1), 64, 0, stream>>>((unsigned*)amaxf);
    k_amax<<<dim3(256, 2), 256, 0, stream>>>(fvs, gvs, (unsigned*)amaxf);
    k_aquant<<<dim3(1024, 2), 256, 0, stream>>>(fvs, gvs, amaxf,
                                                AHf, ALf, AHg, ALg, rsumf, rsumg);
    k_dots<<<dim3((B_ * N_) / 256), 256, 0, stream>>>(x, fw1, fw2, gw1, gw2, alpha,
                                                      e1f, e2f, e1g, e2g, sa);
    k_what2_split<<<dim3(16), 256, 0, stream>>>(w, dvec, W2h, W2l);
    k_amix_split<<<dim3(N_ * N_ / 256), 256, 0, stream>>>(adj, cw, AmixH, AmixL);

    for (int c = 0; c < B_ / BCH; c++) {
        int boff = c * BCH;
        const float* xc  = x  + (size_t)boff * N_ * D_;
        const float* x0c = x0 + (size_t)boff * N_ * D_;
        k_zrs<<<dim3(BCH * N_ / 256), 256, 0, stream>>>(rsEF, rsEG);
        k_xt_split<<<dim3(16, BCH), 256, 0, stream>>>(xc, XTh, XTl);
        k_sigsplit2<<<dim3(16, 16, 2), 256, 0, stream>>>(
            fbs, gbs, e1f + boff * N_, e2f + boff * N_,
            e1g + boff * N_, e2g + boff * N_, SHf, SLf, SHg, SLg);
        k_gemm2i<<<dim3(64, BCH, 2), 256, 0, stream>>>(
            AHf, ALf, AHg, ALg, SHf, SLf, SHg, SLg, rsumf, rsumg, amaxf,
            LF, LG, rsEF, rsEG);
        k_fused<<<dim3(32, BCH), 256, 0, stream>>>(
            LF, LG, rsEF, rsEG, AmixH, AmixL, XTh, XTl, W2h, W2l,
            xc, x0c, sa, cb,
            outf + (size_t)boff * N_ * D_, outg + (size_t)boff * N_ * D_);
    }
}